// Round 1
// baseline (125.192 us; speedup 1.0000x reference)
//
#include <hip/hip_runtime.h>

// Problem constants (fixed by setup_inputs)
constexpr int B_ = 2, C_ = 256, H_ = 160, W_ = 160;
constexpr int N_ = 128, P_ = 7, S_ = 4;
constexpr float SCALE_ = 0.0625f;
constexpr float TRANS_STD_ = 0.1f;
constexpr int HW_ = H_ * W_;           // 25600
constexpr int CELLS_ = P_ * P_;        // 49

// --------------------------------------------------------------------------
// Kernel 1: NCHW -> NHWC transpose. Per batch: (C=256, HW=25600) -> (HW, C).
// 32x32 LDS tiles, block (32,8), each thread moves 4 elements each phase.
// --------------------------------------------------------------------------
__global__ void transpose_nchw_nhwc(const float* __restrict__ in,
                                    float* __restrict__ out) {
    __shared__ float tile[32][33];              // +1 pad: conflict-free
    const int p0 = blockIdx.x * 32;             // pixel tile base
    const int c0 = blockIdx.y * 32;             // channel tile base
    const int b  = blockIdx.z;
    const int tx = threadIdx.x;                 // 0..31
    const int ty = threadIdx.y;                 // 0..7

#pragma unroll
    for (int k = 0; k < 4; ++k) {
        const int c = c0 + ty + 8 * k;
        tile[ty + 8 * k][tx] =
            in[((size_t)b * C_ + c) * HW_ + (p0 + tx)];   // coalesced read
    }
    __syncthreads();
#pragma unroll
    for (int k = 0; k < 4; ++k) {
        const int p = p0 + ty + 8 * k;
        out[((size_t)b * HW_ + p) * C_ + (c0 + tx)] =      // coalesced write
            tile[tx][ty + 8 * k];
    }
}

// --------------------------------------------------------------------------
// Shared per-cell geometry computation (wave-uniform).
// --------------------------------------------------------------------------
struct CellGeom {
    int   b;
    float wstart, hstart, sw, sh;
};

__device__ inline CellGeom cell_geom(const float* __restrict__ rois,
                                     const float* __restrict__ offset,
                                     int n, int ph, int pw, int cell) {
    const float* r = rois + n * 5;
    CellGeom g;
    g.b = (int)r[0];
    // jnp.round is round-half-even -> rintf (default rounding mode)
    const float rsw = rintf(r[1]) * SCALE_ - 0.5f;
    const float rsh = rintf(r[2]) * SCALE_ - 0.5f;
    const float rew = (rintf(r[3]) + 1.0f) * SCALE_ - 0.5f;
    const float reh = (rintf(r[4]) + 1.0f) * SCALE_ - 0.5f;
    const float rw = fmaxf(rew - rsw, 0.1f);
    const float rh = fmaxf(reh - rsh, 0.1f);
    const float bw = rw / (float)P_;
    const float bh = rh / (float)P_;
    g.sw = bw / (float)S_;
    g.sh = bh / (float)S_;
    // part_h == ph, part_w == pw (PART == P == 7)
    const float tx = offset[(n * 2 + 0) * CELLS_ + cell] * TRANS_STD_;
    const float ty = offset[(n * 2 + 1) * CELLS_ + cell] * TRANS_STD_;
    g.wstart = (float)pw * bw + rsw + tx * rw;
    g.hstart = (float)ph * bh + rsh + ty * rh;
    return g;
}

// --------------------------------------------------------------------------
// Kernel 2 (preferred): pooling over NHWC image in d_ws.
// One 64-lane wave per (n,ph,pw) cell; lane t owns channels 4t..4t+3 (float4).
// All control flow wave-uniform (depends only on blockIdx) -> no divergence.
// --------------------------------------------------------------------------
__global__ __launch_bounds__(64) void pool_nhwc(
    const float* __restrict__ img,   // (B,H,W,C)
    const float* __restrict__ rois,
    const float* __restrict__ offset,
    float* __restrict__ out) {
    const int blk  = blockIdx.x;     // n*49 + cell
    const int n    = blk / CELLS_;
    const int cell = blk % CELLS_;
    const int ph   = cell / P_;
    const int pw   = cell % P_;
    const int t    = threadIdx.x;    // channel quad index, 0..63

    const CellGeom g = cell_geom(rois, offset, n, ph, pw, cell);
    const float* base = img + (size_t)g.b * ((size_t)HW_ * C_) + 4 * t;

    float4 acc = make_float4(0.f, 0.f, 0.f, 0.f);
    float  count = 0.0f;

#pragma unroll
    for (int iy = 0; iy < S_; ++iy) {
        const float y = g.hstart + (float)iy * g.sh;
#pragma unroll
        for (int ix = 0; ix < S_; ++ix) {
            const float x = g.wstart + (float)ix * g.sw;
            if (x < -0.5f || x > (float)W_ - 0.5f ||
                y < -0.5f || y > (float)H_ - 0.5f)
                continue;                                   // uniform branch
            count += 1.0f;
            const float xc = fminf(fmaxf(x, 0.0f), (float)(W_ - 1));
            const float yc = fminf(fmaxf(y, 0.0f), (float)(H_ - 1));
            const float x0f = floorf(xc), y0f = floorf(yc);
            const float dx = xc - x0f, dy = yc - y0f;
            const int x0 = (int)x0f,        y0 = (int)y0f;
            const int x1 = (int)ceilf(xc),  y1 = (int)ceilf(yc);
            const float w00 = (1.f - dx) * (1.f - dy);
            const float w01 = (1.f - dx) * dy;
            const float w10 = dx * (1.f - dy);
            const float w11 = dx * dy;
            const float4 v00 = *(const float4*)(base + (size_t)(y0 * W_ + x0) * C_);
            const float4 v01 = *(const float4*)(base + (size_t)(y1 * W_ + x0) * C_);
            const float4 v10 = *(const float4*)(base + (size_t)(y0 * W_ + x1) * C_);
            const float4 v11 = *(const float4*)(base + (size_t)(y1 * W_ + x1) * C_);
            acc.x += w00 * v00.x + w01 * v01.x + w10 * v10.x + w11 * v11.x;
            acc.y += w00 * v00.y + w01 * v01.y + w10 * v10.y + w11 * v11.y;
            acc.z += w00 * v00.z + w01 * v01.z + w10 * v10.z + w11 * v11.z;
            acc.w += w00 * v00.w + w01 * v01.w + w10 * v10.w + w11 * v11.w;
        }
    }

    const float denom = fmaxf(count, 1.0f);
    // out[(n*C + c)*49 + cell], c = 4t..4t+3
    const size_t obase = ((size_t)n * C_ + 4 * t) * CELLS_ + cell;
    out[obase + 0 * CELLS_] = acc.x / denom;
    out[obase + 1 * CELLS_] = acc.y / denom;
    out[obase + 2 * CELLS_] = acc.z / denom;
    out[obase + 3 * CELLS_] = acc.w / denom;
}

// --------------------------------------------------------------------------
// Fallback: pooling straight from NCHW input (used only if ws_size too small
// for the transposed image). Correct but uncoalesced gathers.
// --------------------------------------------------------------------------
__global__ __launch_bounds__(256) void pool_nchw(
    const float* __restrict__ img,   // (B,C,H,W)
    const float* __restrict__ rois,
    const float* __restrict__ offset,
    float* __restrict__ out) {
    const int blk  = blockIdx.x;
    const int n    = blk / CELLS_;
    const int cell = blk % CELLS_;
    const int ph   = cell / P_;
    const int pw   = cell % P_;
    const int c    = threadIdx.x;    // 0..255

    const CellGeom g = cell_geom(rois, offset, n, ph, pw, cell);
    const float* base = img + ((size_t)g.b * C_ + c) * HW_;

    float acc = 0.0f;
    float count = 0.0f;

#pragma unroll
    for (int iy = 0; iy < S_; ++iy) {
        const float y = g.hstart + (float)iy * g.sh;
#pragma unroll
        for (int ix = 0; ix < S_; ++ix) {
            const float x = g.wstart + (float)ix * g.sw;
            if (x < -0.5f || x > (float)W_ - 0.5f ||
                y < -0.5f || y > (float)H_ - 0.5f)
                continue;
            count += 1.0f;
            const float xc = fminf(fmaxf(x, 0.0f), (float)(W_ - 1));
            const float yc = fminf(fmaxf(y, 0.0f), (float)(H_ - 1));
            const float x0f = floorf(xc), y0f = floorf(yc);
            const float dx = xc - x0f, dy = yc - y0f;
            const int x0 = (int)x0f,       y0 = (int)y0f;
            const int x1 = (int)ceilf(xc), y1 = (int)ceilf(yc);
            const float w00 = (1.f - dx) * (1.f - dy);
            const float w01 = (1.f - dx) * dy;
            const float w10 = dx * (1.f - dy);
            const float w11 = dx * dy;
            acc += w00 * base[y0 * W_ + x0] + w01 * base[y1 * W_ + x0] +
                   w10 * base[y0 * W_ + x1] + w11 * base[y1 * W_ + x1];
        }
    }

    out[((size_t)n * C_ + c) * CELLS_ + cell] = acc / fmaxf(count, 1.0f);
}

// --------------------------------------------------------------------------
extern "C" void kernel_launch(void* const* d_in, const int* in_sizes, int n_in,
                              void* d_out, int out_size, void* d_ws, size_t ws_size,
                              hipStream_t stream) {
    const float* inp    = (const float*)d_in[0];
    const float* rois   = (const float*)d_in[1];
    const float* offset = (const float*)d_in[2];
    float* out = (float*)d_out;

    const size_t need = (size_t)B_ * HW_ * C_ * sizeof(float);  // 52.4 MB
    if (ws_size >= need) {
        float* img_nhwc = (float*)d_ws;
        dim3 tg(HW_ / 32, C_ / 32, B_);   // (800, 8, 2)
        dim3 tb(32, 8);
        transpose_nchw_nhwc<<<tg, tb, 0, stream>>>(inp, img_nhwc);
        pool_nhwc<<<N_ * CELLS_, 64, 0, stream>>>(img_nhwc, rois, offset, out);
    } else {
        pool_nchw<<<N_ * CELLS_, 256, 0, stream>>>(inp, rois, offset, out);
    }
}

// Round 2
// 116.179 us; speedup vs baseline: 1.0776x; 1.0776x over previous
//
#include <hip/hip_runtime.h>

// Problem constants (fixed by setup_inputs)
constexpr int B_ = 2, C_ = 256, H_ = 160, W_ = 160;
constexpr int N_ = 128, P_ = 7, S_ = 4;
constexpr float SCALE_ = 0.0625f;
constexpr float TRANS_STD_ = 0.1f;
constexpr int HW_ = H_ * W_;           // 25600
constexpr int CELLS_ = P_ * P_;        // 49

// ---- bf16 helpers (raw ushort payload; RNE) ------------------------------
__device__ inline unsigned short f32_to_bf16(float f) {
    unsigned int u = __float_as_uint(f);
    u += 0x7FFFu + ((u >> 16) & 1u);   // round-to-nearest-even
    return (unsigned short)(u >> 16);
}
__device__ inline float bf16_to_f32(unsigned short h) {
    return __uint_as_float((unsigned int)h << 16);
}

// --------------------------------------------------------------------------
// Kernel 1: NCHW f32 -> NHWC bf16. 64(px) x 64(ch) tiles, 256 threads.
// Reads: float4, 256 B contiguous per row. Writes: ushort4, 128 B per row.
// LDS stores the tile already transposed so phase-2 reads are vectorized.
// --------------------------------------------------------------------------
constexpr int TP_ = 64, TC_ = 64, LDSC_ = TC_ + 4;   // pad keeps ushort4 align

__global__ __launch_bounds__(256) void transpose_bf16(
    const float* __restrict__ in, unsigned short* __restrict__ out) {
    __shared__ unsigned short tile[TP_][LDSC_];      // [pixel][channel]
    const int p0 = blockIdx.x * TP_;
    const int c0 = blockIdx.y * TC_;
    const int b  = blockIdx.z;
    const int tx = threadIdx.x & 15;                 // 0..15
    const int ty = threadIdx.x >> 4;                 // 0..15

#pragma unroll
    for (int k = 0; k < 4; ++k) {
        const int c  = c0 + ty + 16 * k;             // global channel
        const int lp = 4 * tx;                       // tile pixel base
        const float4 v = *(const float4*)
            &in[((size_t)b * C_ + c) * HW_ + p0 + lp];
        const int lc = ty + 16 * k;
        tile[lp + 0][lc] = f32_to_bf16(v.x);
        tile[lp + 1][lc] = f32_to_bf16(v.y);
        tile[lp + 2][lc] = f32_to_bf16(v.z);
        tile[lp + 3][lc] = f32_to_bf16(v.w);
    }
    __syncthreads();
#pragma unroll
    for (int k = 0; k < 4; ++k) {
        const int lp = ty + 16 * k;
        const int p  = p0 + lp;
        const ushort4 w = *(const ushort4*)&tile[lp][4 * tx];
        *(ushort4*)&out[((size_t)b * HW_ + p) * C_ + c0 + 4 * tx] = w;
    }
}

// --------------------------------------------------------------------------
// Shared per-cell geometry computation (wave-uniform).
// --------------------------------------------------------------------------
struct CellGeom {
    int   b;
    float wstart, hstart, sw, sh;
};

__device__ inline CellGeom cell_geom(const float* __restrict__ rois,
                                     const float* __restrict__ offset,
                                     int n, int ph, int pw, int cell) {
    const float* r = rois + n * 5;
    CellGeom g;
    g.b = (int)r[0];
    // jnp.round is round-half-even -> rintf (default rounding mode)
    const float rsw = rintf(r[1]) * SCALE_ - 0.5f;
    const float rsh = rintf(r[2]) * SCALE_ - 0.5f;
    const float rew = (rintf(r[3]) + 1.0f) * SCALE_ - 0.5f;
    const float reh = (rintf(r[4]) + 1.0f) * SCALE_ - 0.5f;
    const float rw = fmaxf(rew - rsw, 0.1f);
    const float rh = fmaxf(reh - rsh, 0.1f);
    const float bw = rw / (float)P_;
    const float bh = rh / (float)P_;
    g.sw = bw / (float)S_;
    g.sh = bh / (float)S_;
    // part_h == ph, part_w == pw (PART == P == 7)
    const float tx = offset[(n * 2 + 0) * CELLS_ + cell] * TRANS_STD_;
    const float ty = offset[(n * 2 + 1) * CELLS_ + cell] * TRANS_STD_;
    g.wstart = (float)pw * bw + rsw + tx * rw;
    g.hstart = (float)ph * bh + rsh + ty * rh;
    return g;
}

// --------------------------------------------------------------------------
// Kernel 2: pooling over bf16 NHWC image in d_ws.
// One 64-lane wave per (n,ph,pw) cell; lane t owns channels 4t..4t+3
// (ushort4 = 8 B/lane, 512 B/wave per corner). Control flow wave-uniform.
// --------------------------------------------------------------------------
__global__ __launch_bounds__(64) void pool_nhwc_bf16(
    const unsigned short* __restrict__ img,   // (B,H,W,C) bf16
    const float* __restrict__ rois,
    const float* __restrict__ offset,
    float* __restrict__ out) {
    const int blk  = blockIdx.x;     // n*49 + cell
    const int n    = blk / CELLS_;
    const int cell = blk % CELLS_;
    const int ph   = cell / P_;
    const int pw   = cell % P_;
    const int t    = threadIdx.x;    // channel quad index, 0..63

    const CellGeom g = cell_geom(rois, offset, n, ph, pw, cell);
    const unsigned short* base =
        img + (size_t)g.b * ((size_t)HW_ * C_) + 4 * t;

    float4 acc = make_float4(0.f, 0.f, 0.f, 0.f);
    float  count = 0.0f;

#pragma unroll
    for (int iy = 0; iy < S_; ++iy) {
        const float y = g.hstart + (float)iy * g.sh;
#pragma unroll
        for (int ix = 0; ix < S_; ++ix) {
            const float x = g.wstart + (float)ix * g.sw;
            if (x < -0.5f || x > (float)W_ - 0.5f ||
                y < -0.5f || y > (float)H_ - 0.5f)
                continue;                                   // uniform branch
            count += 1.0f;
            const float xc = fminf(fmaxf(x, 0.0f), (float)(W_ - 1));
            const float yc = fminf(fmaxf(y, 0.0f), (float)(H_ - 1));
            const float x0f = floorf(xc), y0f = floorf(yc);
            const float dx = xc - x0f, dy = yc - y0f;
            const int x0 = (int)x0f,        y0 = (int)y0f;
            const int x1 = (int)ceilf(xc),  y1 = (int)ceilf(yc);
            const float w00 = (1.f - dx) * (1.f - dy);
            const float w01 = (1.f - dx) * dy;
            const float w10 = dx * (1.f - dy);
            const float w11 = dx * dy;
            const ushort4 u00 = *(const ushort4*)(base + (size_t)(y0 * W_ + x0) * C_);
            const ushort4 u01 = *(const ushort4*)(base + (size_t)(y1 * W_ + x0) * C_);
            const ushort4 u10 = *(const ushort4*)(base + (size_t)(y0 * W_ + x1) * C_);
            const ushort4 u11 = *(const ushort4*)(base + (size_t)(y1 * W_ + x1) * C_);
            acc.x += w00 * bf16_to_f32(u00.x) + w01 * bf16_to_f32(u01.x) +
                     w10 * bf16_to_f32(u10.x) + w11 * bf16_to_f32(u11.x);
            acc.y += w00 * bf16_to_f32(u00.y) + w01 * bf16_to_f32(u01.y) +
                     w10 * bf16_to_f32(u10.y) + w11 * bf16_to_f32(u11.y);
            acc.z += w00 * bf16_to_f32(u00.z) + w01 * bf16_to_f32(u01.z) +
                     w10 * bf16_to_f32(u10.z) + w11 * bf16_to_f32(u11.z);
            acc.w += w00 * bf16_to_f32(u00.w) + w01 * bf16_to_f32(u01.w) +
                     w10 * bf16_to_f32(u10.w) + w11 * bf16_to_f32(u11.w);
        }
    }

    const float denom = fmaxf(count, 1.0f);
    // out[(n*C + c)*49 + cell], c = 4t..4t+3
    const size_t obase = ((size_t)n * C_ + 4 * t) * CELLS_ + cell;
    out[obase + 0 * CELLS_] = acc.x / denom;
    out[obase + 1 * CELLS_] = acc.y / denom;
    out[obase + 2 * CELLS_] = acc.z / denom;
    out[obase + 3 * CELLS_] = acc.w / denom;
}

// --------------------------------------------------------------------------
// Fallback: pooling straight from NCHW f32 input (only if ws too small).
// --------------------------------------------------------------------------
__global__ __launch_bounds__(256) void pool_nchw(
    const float* __restrict__ img,   // (B,C,H,W)
    const float* __restrict__ rois,
    const float* __restrict__ offset,
    float* __restrict__ out) {
    const int blk  = blockIdx.x;
    const int n    = blk / CELLS_;
    const int cell = blk % CELLS_;
    const int ph   = cell / P_;
    const int pw   = cell % P_;
    const int c    = threadIdx.x;    // 0..255

    const CellGeom g = cell_geom(rois, offset, n, ph, pw, cell);
    const float* base = img + ((size_t)g.b * C_ + c) * HW_;

    float acc = 0.0f;
    float count = 0.0f;

#pragma unroll
    for (int iy = 0; iy < S_; ++iy) {
        const float y = g.hstart + (float)iy * g.sh;
#pragma unroll
        for (int ix = 0; ix < S_; ++ix) {
            const float x = g.wstart + (float)ix * g.sw;
            if (x < -0.5f || x > (float)W_ - 0.5f ||
                y < -0.5f || y > (float)H_ - 0.5f)
                continue;
            count += 1.0f;
            const float xc = fminf(fmaxf(x, 0.0f), (float)(W_ - 1));
            const float yc = fminf(fmaxf(y, 0.0f), (float)(H_ - 1));
            const float x0f = floorf(xc), y0f = floorf(yc);
            const float dx = xc - x0f, dy = yc - y0f;
            const int x0 = (int)x0f,       y0 = (int)y0f;
            const int x1 = (int)ceilf(xc), y1 = (int)ceilf(yc);
            const float w00 = (1.f - dx) * (1.f - dy);
            const float w01 = (1.f - dx) * dy;
            const float w10 = dx * (1.f - dy);
            const float w11 = dx * dy;
            acc += w00 * base[y0 * W_ + x0] + w01 * base[y1 * W_ + x0] +
                   w10 * base[y0 * W_ + x1] + w11 * base[y1 * W_ + x1];
        }
    }

    out[((size_t)n * C_ + c) * CELLS_ + cell] = acc / fmaxf(count, 1.0f);
}

// --------------------------------------------------------------------------
extern "C" void kernel_launch(void* const* d_in, const int* in_sizes, int n_in,
                              void* d_out, int out_size, void* d_ws, size_t ws_size,
                              hipStream_t stream) {
    const float* inp    = (const float*)d_in[0];
    const float* rois   = (const float*)d_in[1];
    const float* offset = (const float*)d_in[2];
    float* out = (float*)d_out;

    const size_t need = (size_t)B_ * HW_ * C_ * sizeof(unsigned short); // 26.2 MB
    if (ws_size >= need) {
        unsigned short* img_nhwc = (unsigned short*)d_ws;
        dim3 tg(HW_ / TP_, C_ / TC_, B_);   // (400, 4, 2)
        transpose_bf16<<<tg, 256, 0, stream>>>(inp, img_nhwc);
        pool_nhwc_bf16<<<N_ * CELLS_, 64, 0, stream>>>(img_nhwc, rois, offset, out);
    } else {
        pool_nchw<<<N_ * CELLS_, 256, 0, stream>>>(inp, rois, offset, out);
    }
}